// Round 24
// baseline (127.806 us; speedup 1.0000x reference)
//
#include <hip/hip_runtime.h>

typedef unsigned short u16;
typedef unsigned int u32;
typedef __attribute__((ext_vector_type(8))) short bf16x8;
typedef __attribute__((ext_vector_type(4))) float f32x4;

#define GPTR(p) ((const __attribute__((address_space(1))) void*)(p))
#define SPTR(p) ((__attribute__((address_space(3))) void*)(p))

// ---------- sizes ----------
#define L_SEQ 1024
#define DIM 1024
#define D_INNER 2048
#define D_STATE 64
#define N_HEADS 32
#define NPROJ 4256
#define NPROJ_PAD 4352   // 68 * 64
#define COL_Z 0
#define COL_X 2048
#define COL_B 4096
#define COL_C 4160
#define COL_DT 4224
#define NCHUNK 32
#define QCH 32           // chunk length

__device__ __forceinline__ u16 f2bf(float f) {
    unsigned int u = __float_as_uint(f);
    u = u + 0x7fffu + ((u >> 16) & 1u);   // RNE
    return (u16)(u >> 16);
}
__device__ __forceinline__ float bf2f(u16 h) {
    unsigned int u = ((unsigned int)h) << 16;
    return __uint_as_float(u);
}

// ---------- all input casts in one launch ----------
__global__ __launch_bounds__(256)
void cast_all_kernel(const float* __restrict__ x, const float* __restrict__ W_in,
                     const float* __restrict__ W_out,
                     u16* __restrict__ xb_hi, u16* __restrict__ xb_lo,
                     u16* __restrict__ Winb, u16* __restrict__ Winb_lo,
                     u16* __restrict__ Woutb)
{
    const int b = blockIdx.x;
    if (b < 1024) {                        // x: split hi/lo, 1M elems
        const int i = (b * 256 + threadIdx.x) * 4;
        const float4 v = *(const float4*)&x[i];
        const float vs[4] = { v.x, v.y, v.z, v.w };
        u16 oh[4], ol[4];
        #pragma unroll
        for (int j = 0; j < 4; ++j) {
            oh[j] = f2bf(vs[j]);
            ol[j] = f2bf(vs[j] - bf2f(oh[j]));
        }
        *(ushort4*)&xb_hi[i] = *(ushort4*)oh;
        *(ushort4*)&xb_lo[i] = *(ushort4*)ol;
    } else if (b < 5376) {                 // W_in: pad-cast -> 4352x1024
        const int i = ((b - 1024) * 256 + threadIdx.x) * 4;
        float4 v = make_float4(0.f, 0.f, 0.f, 0.f);
        if (i < NPROJ * DIM) v = *(const float4*)&W_in[i];
        u16 o[4] = { f2bf(v.x), f2bf(v.y), f2bf(v.z), f2bf(v.w) };
        *(ushort4*)&Winb[i] = *(ushort4*)o;
    } else if (b < 5632) {                 // W_in rows 4096..4352: split hi/lo
        const int i = ((b - 5376) * 256 + threadIdx.x) * 4;
        float4 v = make_float4(0.f, 0.f, 0.f, 0.f);
        if (i < (NPROJ - 4096) * DIM) v = *(const float4*)&W_in[(size_t)4096 * DIM + i];
        const float vs[4] = { v.x, v.y, v.z, v.w };
        u16 oh[4], ol[4];
        #pragma unroll
        for (int j = 0; j < 4; ++j) {
            oh[j] = f2bf(vs[j]);
            ol[j] = f2bf(vs[j] - bf2f(oh[j]));
        }
        *(ushort4*)&Winb[(size_t)4096 * DIM + i] = *(ushort4*)oh;
        *(ushort4*)&Winb_lo[i] = *(ushort4*)ol;
    } else {                               // W_out: cast 2M elems
        const int i = ((b - 5632) * 256 + threadIdx.x) * 4;
        const float4 v = *(const float4*)&W_out[i];
        u16 o[4] = { f2bf(v.x), f2bf(v.y), f2bf(v.z), f2bf(v.w) };
        *(ushort4*)&Woutb[i] = *(ushort4*)o;
    }
}

// ---------- bf16 MFMA GEMM, 64x64 tiles, BK=64, swizzled LDS, 2-deep dbuf ----------
// XCD-aware bijective block swizzle (grid % 8 == 0). Uniform 16-iter blocks.
// Normal blocks: C = Ah*Bh^T tile. Precise-slice blocks (GEMM1 only): 3 slices
// per tail tile; slice 0 (hh) writes C, slices 1/2 write Cex planes.
__global__ __launch_bounds__(256, 2)
void gemm_bt64(const u16* __restrict__ Ah, const u16* __restrict__ Al,
               const u16* __restrict__ Bh, const u16* __restrict__ Bl,
               float* __restrict__ C, float* __restrict__ Cex,
               int K, int ldc, int nbx, int nby)
{
    __shared__ u16 As[2][64 * 64];    // [row][64 u16], 128B rows, 8x16B chunks
    __shared__ u16 Bs[2][64 * 64];
    const int tid  = threadIdx.x;
    const int wave = tid >> 6;
    const int lane = tid & 63;
    // XCD swizzle: physical -> logical (bijective, grid multiple of 8)
    const int nwg = gridDim.x;
    const int bx = (blockIdx.x % 8) * (nwg / 8) + blockIdx.x / 8;

    const u16* Asrc;
    const u16* Bsrc;
    int row0, col0, ccol0, ldcd;
    float* Cdst;
    if (bx < nbx * nby) {
        const int cb = bx % nbx;
        const int rb = bx / nbx;
        row0 = rb * 64; col0 = cb * 64;
        Asrc = Ah; Bsrc = Bh;
        Cdst = C; ldcd = ldc; ccol0 = col0;
    } else {
        const int e = bx - nbx * nby;     // 0..191
        const int slice = e >> 6;         // 0..2
        const int idx = e & 63;
        const int cb = idx & 3;
        const int rb = idx >> 2;
        row0 = rb * 64; col0 = nbx * 64 + cb * 64;
        Asrc = (slice == 2) ? Al : Ah;
        Bsrc = (slice == 1) ? Bl : Bh;
        if (slice == 0) { Cdst = C; ldcd = ldc; ccol0 = col0; }
        else            { Cdst = Cex + (size_t)(slice - 1) * (1024 * 256); ldcd = 256; ccol0 = cb * 64; }
    }

    const int wm = (wave >> 1) * 32;
    const int wn = (wave & 1) * 32;
    f32x4 acc[2][2] = {};

    const int r15 = lane & 15;
    const int q4  = lane >> 4;            // 16B-chunk quarter (0..3)
    const int nt = K / 64;

    auto stage = [&](int buf, int kt) {
        #pragma unroll
        for (int call = 0; call < 2; ++call) {
            const int ob = call * 4096 + tid * 16;   // byte in 8KB tile
            const int row = ob >> 7;
            const int chk = (ob >> 4) & 7;
            const int sch = chk ^ (row & 7);         // swizzled source chunk
            const int gk = kt + sch * 8;             // u16 k-offset
            const int lofs = (call * 4096 + wave * 1024) >> 1;  // wave-uniform u16 base
            __builtin_amdgcn_global_load_lds(GPTR(Asrc + (size_t)(row0 + row) * K + gk),
                                             SPTR(&As[buf][lofs]), 16, 0, 0);
            __builtin_amdgcn_global_load_lds(GPTR(Bsrc + (size_t)(col0 + row) * K + gk),
                                             SPTR(&Bs[buf][lofs]), 16, 0, 0);
        }
    };

    stage(0, 0);
    __syncthreads();
    int cur = 0;
    for (int it = 0; it < nt; ++it) {
        if (it + 1 < nt) stage(cur ^ 1, (it + 1) * 64);
        #pragma unroll
        for (int s = 0; s < 2; ++s) {                // two 32-k sub-steps
            const int cbase = s * 4 + q4;            // global 16B chunk 0..7
            bf16x8 av[2], bv[2];
            #pragma unroll
            for (int i = 0; i < 2; ++i) {
                const int r = wm + i * 16 + r15;
                av[i] = *(const bf16x8*)&As[cur][r * 64 + ((cbase ^ (r & 7)) * 8)];
            }
            #pragma unroll
            for (int j = 0; j < 2; ++j) {
                const int r = wn + j * 16 + r15;
                bv[j] = *(const bf16x8*)&Bs[cur][r * 64 + ((cbase ^ (r & 7)) * 8)];
            }
            #pragma unroll
            for (int i = 0; i < 2; ++i)
                #pragma unroll
                for (int j = 0; j < 2; ++j)
                    acc[i][j] = __builtin_amdgcn_mfma_f32_16x16x32_bf16(av[i], bv[j], acc[i][j], 0, 0, 0);
        }
        __syncthreads();
        cur ^= 1;
    }

    const int cl = lane & 15;
    const int rg = (lane >> 4) * 4;
    #pragma unroll
    for (int i = 0; i < 2; ++i)
        #pragma unroll
        for (int j = 0; j < 2; ++j)
            #pragma unroll
            for (int reg = 0; reg < 4; ++reg) {
                const int rrow = row0 + wm + i * 16 + rg + reg;
                const int ccol = ccol0 + wn + j * 16 + cl;
                Cdst[(size_t)rrow * ldcd + ccol] = acc[i][j][reg];
            }
}

// ---------- fused: sliding-window conv+SiLU+xT transpose (blocks 0..255)
//            | dtscan + BC pack with inline Cex fold (blocks 256..383) ----------
__global__ __launch_bounds__(256)
void conv_dt_kernel(const float* __restrict__ P,
                    const float* __restrict__ Cex,
                    const float* __restrict__ Wc,
                    const float* __restrict__ bc,
                    const float* __restrict__ dtb,
                    float* __restrict__ xconv,
                    float* __restrict__ xT,
                    float2* __restrict__ BCp2,
                    float* __restrict__ gT,
                    float* __restrict__ dtsT)
{
    const int b = blockIdx.x;
    if (b < 256) {
        // conv tile: 32 t x 256 c, one channel per thread, sliding 4-tap window
        __shared__ float xls[64][33];
        const int tid = threadIdx.x;
        const int t0 = (b & 31) * 32;
        const int c0 = (b >> 5) * 256;
        const int c = c0 + tid;
        const float w0c = Wc[c * 4 + 0], w1c = Wc[c * 4 + 1];
        const float w2c = Wc[c * 4 + 2], w3c = Wc[c * 4 + 3];
        const float bcv = bc[c];
        float w0 = (t0 >= 3) ? P[(size_t)(t0 - 3) * NPROJ_PAD + COL_X + c] : 0.f;
        float w1 = (t0 >= 2) ? P[(size_t)(t0 - 2) * NPROJ_PAD + COL_X + c] : 0.f;
        float w2 = (t0 >= 1) ? P[(size_t)(t0 - 1) * NPROJ_PAD + COL_X + c] : 0.f;
        float o[32];
        #pragma unroll 8
        for (int tl = 0; tl < 32; ++tl) {
            const int t = t0 + tl;
            const float w3 = P[(size_t)t * NPROJ_PAD + COL_X + c];
            float acc = bcv;
            acc = fmaf(w0, w0c, acc);
            acc = fmaf(w1, w1c, acc);
            acc = fmaf(w2, w2c, acc);
            acc = fmaf(w3, w3c, acc);
            const float v = acc / (1.f + __expf(-acc));   // SiLU
            o[tl] = v;
            xconv[(size_t)t * D_INNER + c] = v;
            w0 = w1; w1 = w2; w2 = w3;
        }
        // transpose write to xT[c][t] via LDS, 64-c sub-tiles (2 at a time)
        #pragma unroll
        for (int r = 0; r < 2; ++r) {
            __syncthreads();
            if ((tid >> 6) == r * 2) {
                #pragma unroll
                for (int tl = 0; tl < 32; ++tl) xls[tid & 63][tl] = o[tl];
            }
            __syncthreads();
            {
                const int row = tid >> 2;         // 0..63
                const int qd  = (tid & 3) * 8;    // 0,8,16,24
                float4 v0, v1;
                v0.x = xls[row][qd + 0]; v0.y = xls[row][qd + 1];
                v0.z = xls[row][qd + 2]; v0.w = xls[row][qd + 3];
                v1.x = xls[row][qd + 4]; v1.y = xls[row][qd + 5];
                v1.z = xls[row][qd + 6]; v1.w = xls[row][qd + 7];
                float* dst = xT + (size_t)(c0 + r * 128 + row) * L_SEQ + t0 + qd;
                *(float4*)dst = v0;
                *(float4*)(dst + 4) = v1;
            }
            __syncthreads();
            if ((tid >> 6) == r * 2 + 1) {
                #pragma unroll
                for (int tl = 0; tl < 32; ++tl) xls[tid & 63][tl] = o[tl];
            }
            __syncthreads();
            {
                const int row = tid >> 2;
                const int qd  = (tid & 3) * 8;
                float4 v0, v1;
                v0.x = xls[row][qd + 0]; v0.y = xls[row][qd + 1];
                v0.z = xls[row][qd + 2]; v0.w = xls[row][qd + 3];
                v1.x = xls[row][qd + 4]; v1.y = xls[row][qd + 5];
                v1.z = xls[row][qd + 6]; v1.w = xls[row][qd + 7];
                float* dst = xT + (size_t)(c0 + r * 128 + 64 + row) * L_SEQ + t0 + qd;
                *(float4*)dst = v0;
                *(float4*)(dst + 4) = v1;
            }
        }
    } else {
        const int b2 = b - 256;                   // 0..127
        const int tid = threadIdx.x;
        // BC pack with inline precise-plane fold (bit-identical to reduce_pe order)
        #pragma unroll
        for (int e = tid; e < 512; e += 256) {
            const int t = b2 * 8 + (e >> 6);
            const int n = e & 63;
            const float peB = Cex[t * 256 + n] + Cex[1024 * 256 + t * 256 + n];
            const float peC = Cex[t * 256 + 64 + n] + Cex[1024 * 256 + t * 256 + 64 + n];
            const float Bv = P[(size_t)t * NPROJ_PAD + COL_B + n] + peB;
            const float Cv = P[(size_t)t * NPROJ_PAD + COL_C + n] + peC;
            BCp2[t * 64 + n] = make_float2(Bv, Cv);
        }
        // dtscan: 4 (h,pr) jobs per block, one per wave; softplus + chunk cumsum
        const int wv = tid >> 6;
        const int lane = tid & 63;
        const int idx = b2 * 4 + wv;   // h*16 + pr
        const int h = idx >> 4;
        const int pr = idx & 15;
        const int t0 = pr * 64;
        const int tt = t0 + lane;
        const float pe = Cex[tt * 256 + 128 + h] + Cex[1024 * 256 + tt * 256 + 128 + h];
        float v = (P[(size_t)tt * NPROJ_PAD + COL_DT + h] + pe) + dtb[h];
        v = (v > 15.f) ? v : __logf(1.f + __expf(v));
        dtsT[h * L_SEQ + tt] = v;
        float g = v;
        #pragma unroll
        for (int off = 1; off < 32; off <<= 1) {
            const float u = __shfl_up(g, off);
            if ((lane & 31) >= off) g += u;
        }
        gT[h * L_SEQ + tt] = g;
    }
}

// ---------- pass 1: local chunk scan; wave = (16 d's, 1 chunk of 32 t), lane = n ----------
__global__ __launch_bounds__(128, 2)
void scan_local_kernel(const float2* __restrict__ BCp2,    // [t][64] (B,C) f32
                       const float* __restrict__ dtsT,     // [h][t] softplus dt
                       const float* __restrict__ A_log,
                       const float* __restrict__ xT,       // [hd][t]
                       float* __restrict__ ygt,            // [t][hd] partial
                       u16* __restrict__ S)                // [hd][32][64] bf16
{
    // pt[wave][step-parity][dd][n+pad] = (p_{d=2dd}, p_{d=2dd+1}) f32; 16.6 KB/block
    __shared__ float2 pt[2][2][8][65];
    const int wv = threadIdx.x >> 6;
    const int lane = threadIdx.x & 63;
    const int hd0 = blockIdx.x * 16;           // block's 16 d's
    const int chunk = blockIdx.y * 2 + wv;     // wave's chunk (0..31)
    const int h = hd0 >> 6;
    const int tb = chunk * QCH;

    const float Av = -__expf(A_log[(size_t)h * 4096 + lane]);   // A for lane's n

    float s[16];
    #pragma unroll
    for (int d = 0; d < 16; ++d) s[d] = 0.f;

    const float2* bc = BCp2 + (size_t)tb * 64 + lane;
    const float* dtp = dtsT + h * L_SEQ + tb;
    const float* xr0 = xT + (size_t)hd0 * L_SEQ + tb;

    // reduce roles: 16 rows (dd 0..7, step parity 0..1) x 4 n-quarters
    const int r16 = lane & 15;
    const int seg = lane >> 4;
    const int rdd = r16 >> 1;         // dd 0..7
    const int ri  = r16 & 1;          // step parity

    #pragma unroll
    for (int g = 0; g < 8; ++g) {     // 8 groups x 4 steps = 32 steps
        // uniform loads for this 4-step group: x (16 d's) + dt (4 scalars)
        const float4 dtg = *(const float4*)(dtp + g * 4);
        const float dta[4] = { dtg.x, dtg.y, dtg.z, dtg.w };
        float xv[16][4];
        #pragma unroll
        for (int d = 0; d < 16; ++d) {
            const float4 a = *(const float4*)(xr0 + d * L_SEQ + g * 4);
            xv[d][0]=a.x; xv[d][1]=a.y; xv[d][2]=a.z; xv[d][3]=a.w;
        }
        #pragma unroll
        for (int half = 0; half < 2; ++half) {   // reduce every 2 steps
            #pragma unroll
            for (int ii2 = 0; ii2 < 2; ++ii2) {
                const int ii = half * 2 + ii2;
                const int i = g * 4 + ii;
                const float2 v = bc[i * 64];
                const float a = __expf(dta[ii] * Av);   // inline decay
                #pragma unroll
                for (int d = 0; d < 16; ++d)
                    s[d] = fmaf(a, s[d], v.x * xv[d][ii]);
                #pragma unroll
                for (int dd = 0; dd < 8; ++dd)
                    pt[wv][ii2][dd][lane] = make_float2(s[2*dd] * v.y, s[2*dd+1] * v.y);
            }
            // wave-private reduce: lane sums one n-quarter of one (dd,parity) row
            float px = 0.f, py = 0.f;
            #pragma unroll
            for (int k = 0; k < 16; ++k) {
                const float2 vv = pt[wv][ri][rdd][seg * 16 + k];
                px += vv.x; py += vv.y;
            }
            px += __shfl_xor(px, 16); py += __shfl_xor(py, 16);
            px += __shfl_xor(px, 32); py += __shfl_xor(py, 32);
            if (lane < 16) {
                const int tA = tb + g * 4 + half * 2 + ri;
                *(float2*)&ygt[(size_t)tA * D_INNER + hd0 + 2 * rdd] = make_float2(px, py);
            }
        }
    }
    #pragma unroll
    for (int d = 0; d < 16; ++d)
        S[((size_t)(hd0 + d) * NCHUNK + chunk) * 64 + lane] = f2bf(s[d]);
}

// ---------- pass 2: chunk-state carry (in place: S -> chunk entry states) ----------
__global__ __launch_bounds__(256)
void chunk_combine_kernel(const float* __restrict__ A_log,
                          const float* __restrict__ gT,
                          u16* __restrict__ S)
{
    const int tid = blockIdx.x * 256 + threadIdx.x;   // hd*64 + n
    const int hd = tid >> 6;
    const int n  = tid & 63;
    const int h  = hd >> 6;
    const float Av = -__expf(A_log[(size_t)hd * 64 + n]);
    float H = 0.f;
    #pragma unroll 8
    for (int c = 0; c < NCHUNK; ++c) {
        const float Gc = gT[h * L_SEQ + c * QCH + QCH - 1];
        const size_t idx = ((size_t)hd * NCHUNK + c) * 64 + n;
        const float Sl = bf2f(S[idx]);
        S[idx] = f2bf(H);                 // entry state for chunk c
        H = __expf(Av * Gc) * H + Sl;
    }
}

// ---------- pass 3 (MFMA): ygt[t][d] += sum_n C'[t,n] * H[n,d] per (h,chunk) ----------
// C values read from packed BCp2 (.y of each (B,C) pair).
__global__ __launch_bounds__(256, 2)
void scan_cross_mfma(const float2* __restrict__ BCp2,
                     const float* __restrict__ gT,
                     const float* __restrict__ A_log,
                     const u16* __restrict__ S,    // entry states bf16
                     float* __restrict__ ygt)      // [t][hd] +=
{
    const int wv = threadIdx.x >> 6;
    const int lane = threadIdx.x & 63;
    const int idx = blockIdx.x * 4 + wv;   // h*32 + chunk
    const int h = idx >> 5;
    const int c = idx & 31;
    const int t0 = c * QCH;
    const int l15 = lane & 15;
    const int lk  = (lane >> 4) * 8;

    float Av8[2][8];
    #pragma unroll
    for (int ss = 0; ss < 2; ++ss)
        #pragma unroll
        for (int qq = 0; qq < 8; ++qq)
            Av8[ss][qq] = -__expf(A_log[(size_t)h * 4096 + ss * 32 + lk + qq]);

    bf16x8 fH[4][2];
    #pragma unroll
    for (int i = 0; i < 4; ++i)
        #pragma unroll
        for (int ss = 0; ss < 2; ++ss)
            fH[i][ss] = *(const bf16x8*)&S[((size_t)(h * 64 + i * 16 + l15) * NCHUNK + c) * 64 + ss * 32 + lk];

    bf16x8 fC[2][2];
    #pragma unroll
    for (int j = 0; j < 2; ++j) {
        const int t = t0 + j * 16 + l15;
        const float g = gT[h * L_SEQ + t];
        #pragma unroll
        for (int ss = 0; ss < 2; ++ss) {
            const float2* src = BCp2 + (size_t)t * 64 + ss * 32 + lk;
            const float4 p0 = *(const float4*)(src);       // B0,C0,B1,C1
            const float4 p1 = *(const float4*)(src + 2);
            const float4 p2 = *(const float4*)(src + 4);
            const float4 p3 = *(const float4*)(src + 6);
            const float v[8] = { p0.y, p0.w, p1.y, p1.w, p2.y, p2.w, p3.y, p3.w };
            bf16x8 rr;
            #pragma unroll
            for (int qq = 0; qq < 8; ++qq)
                rr[qq] = (short)f2bf(v[qq] * __expf(Av8[ss][qq] * g));
            fC[j][ss] = rr;
        }
    }

    f32x4 acc[2][4] = {};   // [t-tile][d-tile]
    #pragma unroll
    for (int ss = 0; ss < 2; ++ss)
        #pragma unroll
        for (int j = 0; j < 2; ++j)
            #pragma unroll
            for (int i = 0; i < 4; ++i)
                acc[j][i] = __builtin_amdgcn_mfma_f32_16x16x32_bf16(fC[j][ss], fH[i][ss], acc[j][i], 0, 0, 0);

    const int rg = (lane >> 4) * 4;
    #pragma unroll
    for (int j = 0; j < 2; ++j)
        #pragma unroll
        for (int i = 0; i < 4; ++i)
            #pragma unroll
            for (int rr = 0; rr < 4; ++rr) {
                const int t = t0 + j * 16 + rg + rr;
                const int d = h * 64 + i * 16 + l15;
                ygt[(size_t)t * D_INNER + d] += acc[j][i][rr];   // coalesced
            }
}

// ---------- RMSNorm + skip(D*x) + gate + cast to bf16 ----------
__global__ __launch_bounds__(256)
void rmsnorm_kernel(const float* __restrict__ ygt,  // [t][hd]
                    const float* __restrict__ P,    // z columns
                    const float* __restrict__ xconv,
                    const float* __restrict__ Dp,
                    const float* __restrict__ nw,
                    u16* __restrict__ Yb)           // [t][hd] bf16
{
    __shared__ float red[4];
    const int t = blockIdx.x;
    const int tid = threadIdx.x;
    const int c0 = tid * 8;
    const float* zrow = P + (size_t)t * NPROJ_PAD + COL_Z + c0;
    const float4 z0 = *(const float4*)zrow;
    const float4 z1 = *(const float4*)(zrow + 4);
    const float zz[8] = { z0.x, z0.y, z0.z, z0.w, z1.x, z1.y, z1.z, z1.w };
    const float* xrow = xconv + (size_t)t * D_INNER + c0;
    const float4 x0 = *(const float4*)xrow;
    const float4 x1 = *(const float4*)(xrow + 4);
    const float xx[8] = { x0.x, x0.y, x0.z, x0.w, x1.x, x1.y, x1.z, x1.w };
    const float4 d0 = *(const float4*)&Dp[c0];
    const float4 d1 = *(const float4*)&Dp[c0 + 4];
    const float dd[8] = { d0.x, d0.y, d0.z, d0.w, d1.x, d1.y, d1.z, d1.w };
    const float* yrow = ygt + (size_t)t * D_INNER + c0;
    const float4 y0 = *(const float4*)yrow;
    const float4 y1 = *(const float4*)(yrow + 4);
    const float yy[8] = { y0.x, y0.y, y0.z, y0.w, y1.x, y1.y, y1.z, y1.w };
    float v[8];
    float ss = 0.f;
    #pragma unroll
    for (int j = 0; j < 8; ++j) {
        const float yv = yy[j] + dd[j] * xx[j];
        const float z = zz[j];
        const float gated = yv * (z / (1.f + __expf(-z)));
        v[j] = gated;
        ss += gated * gated;
    }
    #pragma unroll
    for (int off = 32; off > 0; off >>= 1) ss += __shfl_xor(ss, off);
    const int wave = tid >> 6;
    if ((tid & 63) == 0) red[wave] = ss;
    __syncthreads();
    const float total = red[0] + red[1] + red[2] + red[3];
    const float scale = rsqrtf(total * (1.f / D_INNER) + 1e-6f);
    u16 o[8];
    #pragma unroll
    for (int j = 0; j < 8; ++j)
        o[j] = f2bf(v[j] * scale * nw[c0 + j]);
    *(uint4*)&Yb[(size_t)t * D_INNER + c0] = *(uint4*)o;
}

// ---------- launcher ----------
extern "C" void kernel_launch(void* const* d_in, const int* in_sizes, int n_in,
                              void* d_out, int out_size, void* d_ws, size_t ws_size,
                              hipStream_t stream)
{
    const float* x      = (const float*)d_in[0];
    const float* W_in   = (const float*)d_in[1];
    const float* W_conv = (const float*)d_in[2];
    const float* b_conv = (const float*)d_in[3];
    const float* A_log  = (const float*)d_in[4];
    const float* Dp     = (const float*)d_in[5];
    const float* dt_bias= (const float*)d_in[6];
    const float* norm_w = (const float*)d_in[7];
    const float* W_out  = (const float*)d_in[8];
    float* out = (float*)d_out;

    // Workspace layout (MiB). Cex now consumed by conv_dt (dead before scan).
    char* w = (char*)d_ws;
    u16*   xb_hi  = (u16*)(w);                         //  0-2   (dead after GEMM1)
    u16*   xb_lo  = (u16*)(w + (2u  << 20));           //  2-4   (dead after GEMM1)
    u16*   Winb   = (u16*)(w + (4u  << 20));           //  4-12.5(dead after GEMM1)
    u16*   Winb_lo= (u16*)(w + (12u << 20) + (512u << 10)); // 12.5-13 (dead after GEMM1)
    float* Cex    = (float*)(w + (13u << 20));         // 13-15  (dead after conv_dt)
    u16*   Yb     = (u16*)(w);                         //  0-4   (after GEMM1 inputs dead)
    u16*   S      = (u16*)(w + (8u  << 20));           //  8-16  bf16 [hd][32][64]
    u16*   Woutb  = (u16*)(w + (16u << 20));           // 16-20
    float* P      = (float*)(w + (20u << 20));         // 20-37  (1024x4352)
    float* xconv  = (float*)(w + (37u << 20));         // 37-45
    float* gT     = (float*)(w + (45u << 20));         // 45-45.125 [h][t]
    float* dtsT   = (float*)(w + (45u << 20) + (128u << 10)); // 45.125-45.25 [h][t]
    float2* BCp2  = (float2*)(w + (45u << 20) + (512u << 10)); // 45.5-46 [t][64]
    float* ygt    = (float*)(w + (46u << 20));         // 46-54  [t][hd]
    float* xT     = (float*)(w + (54u << 20));         // 54-62  [hd][t]

    const u16* Winb_lo_virt = Winb_lo - (size_t)4096 * DIM;

    // 1. all input casts in one launch
    cast_all_kernel<<<dim3(7680), 256, 0, stream>>>(
        x, W_in, W_out, xb_hi, xb_lo, Winb, Winb_lo, Woutb);

    // 2. in-projection GEMM, load-balanced + XCD-swizzled: 1024 + 192 blocks
    gemm_bt64<<<dim3(1024 + 192), 256, 0, stream>>>(
        xb_hi, xb_lo, Winb, Winb_lo_virt, P, Cex, DIM, NPROJ_PAD, 64, 16);

    // 3. fused sliding conv+SiLU+xT | dtscan + BC pack (with inline Cex fold)
    conv_dt_kernel<<<dim3(256 + 128), 256, 0, stream>>>(
        P, Cex, W_conv, b_conv, dt_bias, xconv, xT, BCp2, gT, dtsT);

    // 4. chunked selective scan (16 d x 1 chunk per wave, inline decay)
    scan_local_kernel<<<dim3(D_INNER / 16, 16), 128, 0, stream>>>(
        BCp2, dtsT, A_log, xT, ygt, S);
    chunk_combine_kernel<<<dim3(D_INNER * 64 / 256), 256, 0, stream>>>(A_log, gT, S);
    scan_cross_mfma<<<dim3(N_HEADS * NCHUNK / 4), 256, 0, stream>>>(BCp2, gT, A_log, S, ygt);

    // 5. skip + gate + RMSNorm + bf16 cast
    rmsnorm_kernel<<<dim3(L_SEQ), 256, 0, stream>>>(ygt, P, xconv, Dp, norm_w, Yb);

    // 6. out-projection GEMM: out = Y @ W_out^T (256 blocks, XCD-swizzled)
    gemm_bt64<<<dim3(256), 256, 0, stream>>>(
        Yb, (const u16*)nullptr, Woutb, (const u16*)nullptr, out, (float*)nullptr,
        D_INNER, DIM, 16, 16);
}

// Round 25
// 126.295 us; speedup vs baseline: 1.0120x; 1.0120x over previous
//
#include <hip/hip_runtime.h>

typedef unsigned short u16;
typedef unsigned int u32;
typedef __attribute__((ext_vector_type(8))) short bf16x8;
typedef __attribute__((ext_vector_type(4))) float f32x4;

#define GPTR(p) ((const __attribute__((address_space(1))) void*)(p))
#define SPTR(p) ((__attribute__((address_space(3))) void*)(p))

// ---------- sizes ----------
#define L_SEQ 1024
#define DIM 1024
#define D_INNER 2048
#define D_STATE 64
#define N_HEADS 32
#define NPROJ 4256
#define NPROJ_PAD 4352   // 68 * 64
#define COL_Z 0
#define COL_X 2048
#define COL_B 4096
#define COL_C 4160
#define COL_DT 4224
#define NCHUNK 32
#define QCH 32           // chunk length

__device__ __forceinline__ u16 f2bf(float f) {
    unsigned int u = __float_as_uint(f);
    u = u + 0x7fffu + ((u >> 16) & 1u);   // RNE
    return (u16)(u >> 16);
}
__device__ __forceinline__ float bf2f(u16 h) {
    unsigned int u = ((unsigned int)h) << 16;
    return __uint_as_float(u);
}

// ---------- input casts (x, W_in) in one launch; W_out cast hidden in conv_dt ----------
__global__ __launch_bounds__(256)
void cast_all_kernel(const float* __restrict__ x, const float* __restrict__ W_in,
                     u16* __restrict__ xb_hi, u16* __restrict__ xb_lo,
                     u16* __restrict__ Winb, u16* __restrict__ Winb_lo)
{
    const int b = blockIdx.x;
    if (b < 1024) {                        // x: split hi/lo, 1M elems
        const int i = (b * 256 + threadIdx.x) * 4;
        const float4 v = *(const float4*)&x[i];
        const float vs[4] = { v.x, v.y, v.z, v.w };
        u16 oh[4], ol[4];
        #pragma unroll
        for (int j = 0; j < 4; ++j) {
            oh[j] = f2bf(vs[j]);
            ol[j] = f2bf(vs[j] - bf2f(oh[j]));
        }
        *(ushort4*)&xb_hi[i] = *(ushort4*)oh;
        *(ushort4*)&xb_lo[i] = *(ushort4*)ol;
    } else if (b < 5376) {                 // W_in: pad-cast -> 4352x1024
        const int i = ((b - 1024) * 256 + threadIdx.x) * 4;
        float4 v = make_float4(0.f, 0.f, 0.f, 0.f);
        if (i < NPROJ * DIM) v = *(const float4*)&W_in[i];
        u16 o[4] = { f2bf(v.x), f2bf(v.y), f2bf(v.z), f2bf(v.w) };
        *(ushort4*)&Winb[i] = *(ushort4*)o;
    } else {                               // W_in rows 4096..4352: split hi/lo
        const int i = ((b - 5376) * 256 + threadIdx.x) * 4;
        float4 v = make_float4(0.f, 0.f, 0.f, 0.f);
        if (i < (NPROJ - 4096) * DIM) v = *(const float4*)&W_in[(size_t)4096 * DIM + i];
        const float vs[4] = { v.x, v.y, v.z, v.w };
        u16 oh[4], ol[4];
        #pragma unroll
        for (int j = 0; j < 4; ++j) {
            oh[j] = f2bf(vs[j]);
            ol[j] = f2bf(vs[j] - bf2f(oh[j]));
        }
        *(ushort4*)&Winb[(size_t)4096 * DIM + i] = *(ushort4*)oh;
        *(ushort4*)&Winb_lo[i] = *(ushort4*)ol;
    }
}

// ---------- bf16 MFMA GEMM, 64x64 tiles, BK=64, swizzled LDS, 2-deep dbuf ----------
// Uniform 16-iter blocks. Normal blocks: C = Ah*Bh^T tile. Precise-slice blocks
// (GEMM1 only): 3 slices per tail tile; slice 0 (hh) writes C, slices 1/2 write Cex.
__global__ __launch_bounds__(256, 2)
void gemm_bt64(const u16* __restrict__ Ah, const u16* __restrict__ Al,
               const u16* __restrict__ Bh, const u16* __restrict__ Bl,
               float* __restrict__ C, float* __restrict__ Cex,
               int K, int ldc, int nbx, int nby)
{
    __shared__ u16 As[2][64 * 64];    // [row][64 u16], 128B rows, 8x16B chunks
    __shared__ u16 Bs[2][64 * 64];
    const int tid  = threadIdx.x;
    const int wave = tid >> 6;
    const int lane = tid & 63;
    const int bx = blockIdx.x;

    const u16* Asrc;
    const u16* Bsrc;
    int row0, col0, ccol0, ldcd;
    float* Cdst;
    if (bx < nbx * nby) {
        const int cb = bx % nbx;
        const int rb = bx / nbx;
        row0 = rb * 64; col0 = cb * 64;
        Asrc = Ah; Bsrc = Bh;
        Cdst = C; ldcd = ldc; ccol0 = col0;
    } else {
        const int e = bx - nbx * nby;     // 0..191
        const int slice = e >> 6;         // 0..2
        const int idx = e & 63;
        const int cb = idx & 3;
        const int rb = idx >> 2;
        row0 = rb * 64; col0 = nbx * 64 + cb * 64;
        Asrc = (slice == 2) ? Al : Ah;
        Bsrc = (slice == 1) ? Bl : Bh;
        if (slice == 0) { Cdst = C; ldcd = ldc; ccol0 = col0; }
        else            { Cdst = Cex + (size_t)(slice - 1) * (1024 * 256); ldcd = 256; ccol0 = cb * 64; }
    }

    const int wm = (wave >> 1) * 32;
    const int wn = (wave & 1) * 32;
    f32x4 acc[2][2] = {};

    const int r15 = lane & 15;
    const int q4  = lane >> 4;            // 16B-chunk quarter (0..3)
    const int nt = K / 64;

    auto stage = [&](int buf, int kt) {
        #pragma unroll
        for (int call = 0; call < 2; ++call) {
            const int ob = call * 4096 + tid * 16;   // byte in 8KB tile
            const int row = ob >> 7;
            const int chk = (ob >> 4) & 7;
            const int sch = chk ^ (row & 7);         // swizzled source chunk
            const int gk = kt + sch * 8;             // u16 k-offset
            const int lofs = (call * 4096 + wave * 1024) >> 1;  // wave-uniform u16 base
            __builtin_amdgcn_global_load_lds(GPTR(Asrc + (size_t)(row0 + row) * K + gk),
                                             SPTR(&As[buf][lofs]), 16, 0, 0);
            __builtin_amdgcn_global_load_lds(GPTR(Bsrc + (size_t)(col0 + row) * K + gk),
                                             SPTR(&Bs[buf][lofs]), 16, 0, 0);
        }
    };

    stage(0, 0);
    __syncthreads();
    int cur = 0;
    for (int it = 0; it < nt; ++it) {
        if (it + 1 < nt) stage(cur ^ 1, (it + 1) * 64);
        #pragma unroll
        for (int s = 0; s < 2; ++s) {                // two 32-k sub-steps
            const int cbase = s * 4 + q4;            // global 16B chunk 0..7
            bf16x8 av[2], bv[2];
            #pragma unroll
            for (int i = 0; i < 2; ++i) {
                const int r = wm + i * 16 + r15;
                av[i] = *(const bf16x8*)&As[cur][r * 64 + ((cbase ^ (r & 7)) * 8)];
            }
            #pragma unroll
            for (int j = 0; j < 2; ++j) {
                const int r = wn + j * 16 + r15;
                bv[j] = *(const bf16x8*)&Bs[cur][r * 64 + ((cbase ^ (r & 7)) * 8)];
            }
            #pragma unroll
            for (int i = 0; i < 2; ++i)
                #pragma unroll
                for (int j = 0; j < 2; ++j)
                    acc[i][j] = __builtin_amdgcn_mfma_f32_16x16x32_bf16(av[i], bv[j], acc[i][j], 0, 0, 0);
        }
        __syncthreads();
        cur ^= 1;
    }

    const int cl = lane & 15;
    const int rg = (lane >> 4) * 4;
    #pragma unroll
    for (int i = 0; i < 2; ++i)
        #pragma unroll
        for (int j = 0; j < 2; ++j)
            #pragma unroll
            for (int reg = 0; reg < 4; ++reg) {
                const int rrow = row0 + wm + i * 16 + rg + reg;
                const int ccol = ccol0 + wn + j * 16 + cl;
                Cdst[(size_t)rrow * ldcd + ccol] = acc[i][j][reg];
            }
}

// ---------- fused: sliding-window conv+SiLU+xT (blocks 0..255)
//            | dtscan + BC pack with inline Cex fold (blocks 256..383)
//            | W_out bf16 cast (blocks 384..2431, hidden under conv latency) ----------
__global__ __launch_bounds__(256)
void conv_dt_kernel(const float* __restrict__ P,
                    const float* __restrict__ Cex,
                    const float* __restrict__ Wc,
                    const float* __restrict__ bc,
                    const float* __restrict__ dtb,
                    const float* __restrict__ W_out,
                    float* __restrict__ xconv,
                    float* __restrict__ xT,
                    float2* __restrict__ BCp2,
                    float* __restrict__ gT,
                    float* __restrict__ dtsT,
                    u16* __restrict__ Woutb)
{
    const int b = blockIdx.x;
    if (b < 256) {
        // conv tile: 32 t x 256 c, one channel per thread, sliding 4-tap window
        __shared__ float xls[64][33];
        const int tid = threadIdx.x;
        const int t0 = (b & 31) * 32;
        const int c0 = (b >> 5) * 256;
        const int c = c0 + tid;
        const float w0c = Wc[c * 4 + 0], w1c = Wc[c * 4 + 1];
        const float w2c = Wc[c * 4 + 2], w3c = Wc[c * 4 + 3];
        const float bcv = bc[c];
        float w0 = (t0 >= 3) ? P[(size_t)(t0 - 3) * NPROJ_PAD + COL_X + c] : 0.f;
        float w1 = (t0 >= 2) ? P[(size_t)(t0 - 2) * NPROJ_PAD + COL_X + c] : 0.f;
        float w2 = (t0 >= 1) ? P[(size_t)(t0 - 1) * NPROJ_PAD + COL_X + c] : 0.f;
        float o[32];
        #pragma unroll 8
        for (int tl = 0; tl < 32; ++tl) {
            const int t = t0 + tl;
            const float w3 = P[(size_t)t * NPROJ_PAD + COL_X + c];
            float acc = bcv;
            acc = fmaf(w0, w0c, acc);
            acc = fmaf(w1, w1c, acc);
            acc = fmaf(w2, w2c, acc);
            acc = fmaf(w3, w3c, acc);
            const float v = acc / (1.f + __expf(-acc));   // SiLU
            o[tl] = v;
            xconv[(size_t)t * D_INNER + c] = v;
            w0 = w1; w1 = w2; w2 = w3;
        }
        // transpose write to xT[c][t] via LDS, 64-c sub-tiles (2 at a time)
        #pragma unroll
        for (int r = 0; r < 2; ++r) {
            __syncthreads();
            if ((tid >> 6) == r * 2) {
                #pragma unroll
                for (int tl = 0; tl < 32; ++tl) xls[tid & 63][tl] = o[tl];
            }
            __syncthreads();
            {
                const int row = tid >> 2;         // 0..63
                const int qd  = (tid & 3) * 8;    // 0,8,16,24
                float4 v0, v1;
                v0.x = xls[row][qd + 0]; v0.y = xls[row][qd + 1];
                v0.z = xls[row][qd + 2]; v0.w = xls[row][qd + 3];
                v1.x = xls[row][qd + 4]; v1.y = xls[row][qd + 5];
                v1.z = xls[row][qd + 6]; v1.w = xls[row][qd + 7];
                float* dst = xT + (size_t)(c0 + r * 128 + row) * L_SEQ + t0 + qd;
                *(float4*)dst = v0;
                *(float4*)(dst + 4) = v1;
            }
            __syncthreads();
            if ((tid >> 6) == r * 2 + 1) {
                #pragma unroll
                for (int tl = 0; tl < 32; ++tl) xls[tid & 63][tl] = o[tl];
            }
            __syncthreads();
            {
                const int row = tid >> 2;
                const int qd  = (tid & 3) * 8;
                float4 v0, v1;
                v0.x = xls[row][qd + 0]; v0.y = xls[row][qd + 1];
                v0.z = xls[row][qd + 2]; v0.w = xls[row][qd + 3];
                v1.x = xls[row][qd + 4]; v1.y = xls[row][qd + 5];
                v1.z = xls[row][qd + 6]; v1.w = xls[row][qd + 7];
                float* dst = xT + (size_t)(c0 + r * 128 + 64 + row) * L_SEQ + t0 + qd;
                *(float4*)dst = v0;
                *(float4*)(dst + 4) = v1;
            }
        }
    } else if (b < 384) {
        const int b2 = b - 256;                   // 0..127
        const int tid = threadIdx.x;
        // BC pack with inline precise-plane fold (bit-identical to reduce_pe order)
        #pragma unroll
        for (int e = tid; e < 512; e += 256) {
            const int t = b2 * 8 + (e >> 6);
            const int n = e & 63;
            const float peB = Cex[t * 256 + n] + Cex[1024 * 256 + t * 256 + n];
            const float peC = Cex[t * 256 + 64 + n] + Cex[1024 * 256 + t * 256 + 64 + n];
            const float Bv = P[(size_t)t * NPROJ_PAD + COL_B + n] + peB;
            const float Cv = P[(size_t)t * NPROJ_PAD + COL_C + n] + peC;
            BCp2[t * 64 + n] = make_float2(Bv, Cv);
        }
        // dtscan: 4 (h,pr) jobs per block, one per wave; softplus + chunk cumsum
        const int wv = tid >> 6;
        const int lane = tid & 63;
        const int idx = b2 * 4 + wv;   // h*16 + pr
        const int h = idx >> 4;
        const int pr = idx & 15;
        const int t0 = pr * 64;
        const int tt = t0 + lane;
        const float pe = Cex[tt * 256 + 128 + h] + Cex[1024 * 256 + tt * 256 + 128 + h];
        float v = (P[(size_t)tt * NPROJ_PAD + COL_DT + h] + pe) + dtb[h];
        v = (v > 15.f) ? v : __logf(1.f + __expf(v));
        dtsT[h * L_SEQ + tt] = v;
        float g = v;
        #pragma unroll
        for (int off = 1; off < 32; off <<= 1) {
            const float u = __shfl_up(g, off);
            if ((lane & 31) >= off) g += u;
        }
        gT[h * L_SEQ + tt] = g;
    } else {
        // W_out cast: 2048 blocks cover 2M elems (independent of P; needed by GEMM2)
        const int i = ((b - 384) * 256 + threadIdx.x) * 4;
        const float4 v = *(const float4*)&W_out[i];
        u16 o[4] = { f2bf(v.x), f2bf(v.y), f2bf(v.z), f2bf(v.w) };
        *(ushort4*)&Woutb[i] = *(ushort4*)o;
    }
}

// ---------- pass 1: local chunk scan; wave = (16 d's, 1 chunk of 32 t), lane = n ----------
__global__ __launch_bounds__(128, 2)
void scan_local_kernel(const float2* __restrict__ BCp2,    // [t][64] (B,C) f32
                       const float* __restrict__ dtsT,     // [h][t] softplus dt
                       const float* __restrict__ A_log,
                       const float* __restrict__ xT,       // [hd][t]
                       float* __restrict__ ygt,            // [t][hd] partial
                       u16* __restrict__ S)                // [hd][32][64] bf16
{
    // pt[wave][step-parity][dd][n+pad] = (p_{d=2dd}, p_{d=2dd+1}) f32; 16.6 KB/block
    __shared__ float2 pt[2][2][8][65];
    const int wv = threadIdx.x >> 6;
    const int lane = threadIdx.x & 63;
    const int hd0 = blockIdx.x * 16;           // block's 16 d's
    const int chunk = blockIdx.y * 2 + wv;     // wave's chunk (0..31)
    const int h = hd0 >> 6;
    const int tb = chunk * QCH;

    const float Av = -__expf(A_log[(size_t)h * 4096 + lane]);   // A for lane's n

    float s[16];
    #pragma unroll
    for (int d = 0; d < 16; ++d) s[d] = 0.f;

    const float2* bc = BCp2 + (size_t)tb * 64 + lane;
    const float* dtp = dtsT + h * L_SEQ + tb;
    const float* xr0 = xT + (size_t)hd0 * L_SEQ + tb;

    // reduce roles: 16 rows (dd 0..7, step parity 0..1) x 4 n-quarters
    const int r16 = lane & 15;
    const int seg = lane >> 4;
    const int rdd = r16 >> 1;         // dd 0..7
    const int ri  = r16 & 1;          // step parity

    #pragma unroll
    for (int g = 0; g < 8; ++g) {     // 8 groups x 4 steps = 32 steps
        const float4 dtg = *(const float4*)(dtp + g * 4);
        const float dta[4] = { dtg.x, dtg.y, dtg.z, dtg.w };
        float xv[16][4];
        #pragma unroll
        for (int d = 0; d < 16; ++d) {
            const float4 a = *(const float4*)(xr0 + d * L_SEQ + g * 4);
            xv[d][0]=a.x; xv[d][1]=a.y; xv[d][2]=a.z; xv[d][3]=a.w;
        }
        #pragma unroll
        for (int half = 0; half < 2; ++half) {   // reduce every 2 steps
            #pragma unroll
            for (int ii2 = 0; ii2 < 2; ++ii2) {
                const int ii = half * 2 + ii2;
                const int i = g * 4 + ii;
                const float2 v = bc[i * 64];
                const float a = __expf(dta[ii] * Av);   // inline decay
                #pragma unroll
                for (int d = 0; d < 16; ++d)
                    s[d] = fmaf(a, s[d], v.x * xv[d][ii]);
                #pragma unroll
                for (int dd = 0; dd < 8; ++dd)
                    pt[wv][ii2][dd][lane] = make_float2(s[2*dd] * v.y, s[2*dd+1] * v.y);
            }
            float px = 0.f, py = 0.f;
            #pragma unroll
            for (int k = 0; k < 16; ++k) {
                const float2 vv = pt[wv][ri][rdd][seg * 16 + k];
                px += vv.x; py += vv.y;
            }
            px += __shfl_xor(px, 16); py += __shfl_xor(py, 16);
            px += __shfl_xor(px, 32); py += __shfl_xor(py, 32);
            if (lane < 16) {
                const int tA = tb + g * 4 + half * 2 + ri;
                *(float2*)&ygt[(size_t)tA * D_INNER + hd0 + 2 * rdd] = make_float2(px, py);
            }
        }
    }
    #pragma unroll
    for (int d = 0; d < 16; ++d)
        S[((size_t)(hd0 + d) * NCHUNK + chunk) * 64 + lane] = f2bf(s[d]);
}

// ---------- pass 2: chunk-state carry (in place: S -> chunk entry states) ----------
__global__ __launch_bounds__(256)
void chunk_combine_kernel(const float* __restrict__ A_log,
                          const float* __restrict__ gT,
                          u16* __restrict__ S)
{
    const int tid = blockIdx.x * 256 + threadIdx.x;   // hd*64 + n
    const int hd = tid >> 6;
    const int n  = tid & 63;
    const int h  = hd >> 6;
    const float Av = -__expf(A_log[(size_t)hd * 64 + n]);
    float H = 0.f;
    #pragma unroll 8
    for (int c = 0; c < NCHUNK; ++c) {
        const float Gc = gT[h * L_SEQ + c * QCH + QCH - 1];
        const size_t idx = ((size_t)hd * NCHUNK + c) * 64 + n;
        const float Sl = bf2f(S[idx]);
        S[idx] = f2bf(H);                 // entry state for chunk c
        H = __expf(Av * Gc) * H + Sl;
    }
}

// ---------- pass 3 (MFMA): ygt[t][d] += sum_n C'[t,n] * H[n,d] per (h,chunk) ----------
__global__ __launch_bounds__(256, 2)
void scan_cross_mfma(const float2* __restrict__ BCp2,
                     const float* __restrict__ gT,
                     const float* __restrict__ A_log,
                     const u16* __restrict__ S,    // entry states bf16
                     float* __restrict__ ygt)      // [t][hd] +=
{
    const int wv = threadIdx.x >> 6;
    const int lane = threadIdx.x & 63;
    const int idx = blockIdx.x * 4 + wv;   // h*32 + chunk
    const int h = idx >> 5;
    const int c = idx & 31;
    const int t0 = c * QCH;
    const int l15 = lane & 15;
    const int lk  = (lane >> 4) * 8;

    float Av8[2][8];
    #pragma unroll
    for (int ss = 0; ss < 2; ++ss)
        #pragma unroll
        for (int qq = 0; qq < 8; ++qq)
            Av8[ss][qq] = -__expf(A_log[(size_t)h * 4096 + ss * 32 + lk + qq]);

    bf16x8 fH[4][2];
    #pragma unroll
    for (int i = 0; i < 4; ++i)
        #pragma unroll
        for (int ss = 0; ss < 2; ++ss)
            fH[i][ss] = *(const bf16x8*)&S[((size_t)(h * 64 + i * 16 + l15) * NCHUNK + c) * 64 + ss * 32 + lk];

    bf16x8 fC[2][2];
    #pragma unroll
    for (int j = 0; j < 2; ++j) {
        const int t = t0 + j * 16 + l15;
        const float g = gT[h * L_SEQ + t];
        #pragma unroll
        for (int ss = 0; ss < 2; ++ss) {
            const float2* src = BCp2 + (size_t)t * 64 + ss * 32 + lk;
            const float4 p0 = *(const float4*)(src);       // B0,C0,B1,C1
            const float4 p1 = *(const float4*)(src + 2);
            const float4 p2 = *(const float4*)(src + 4);
            const float4 p3 = *(const float4*)(src + 6);
            const float v[8] = { p0.y, p0.w, p1.y, p1.w, p2.y, p2.w, p3.y, p3.w };
            bf16x8 rr;
            #pragma unroll
            for (int qq = 0; qq < 8; ++qq)
                rr[qq] = (short)f2bf(v[qq] * __expf(Av8[ss][qq] * g));
            fC[j][ss] = rr;
        }
    }

    f32x4 acc[2][4] = {};   // [t-tile][d-tile]
    #pragma unroll
    for (int ss = 0; ss < 2; ++ss)
        #pragma unroll
        for (int j = 0; j < 2; ++j)
            #pragma unroll
            for (int i = 0; i < 4; ++i)
                acc[j][i] = __builtin_amdgcn_mfma_f32_16x16x32_bf16(fC[j][ss], fH[i][ss], acc[j][i], 0, 0, 0);

    const int rg = (lane >> 4) * 4;
    #pragma unroll
    for (int j = 0; j < 2; ++j)
        #pragma unroll
        for (int i = 0; i < 4; ++i)
            #pragma unroll
            for (int rr = 0; rr < 4; ++rr) {
                const int t = t0 + j * 16 + rg + rr;
                const int d = h * 64 + i * 16 + l15;
                ygt[(size_t)t * D_INNER + d] += acc[j][i][rr];   // coalesced
            }
}

// ---------- RMSNorm + skip(D*x) + gate + cast to bf16 ----------
__global__ __launch_bounds__(256)
void rmsnorm_kernel(const float* __restrict__ ygt,  // [t][hd]
                    const float* __restrict__ P,    // z columns
                    const float* __restrict__ xconv,
                    const float* __restrict__ Dp,
                    const float* __restrict__ nw,
                    u16* __restrict__ Yb)           // [t][hd] bf16
{
    __shared__ float red[4];
    const int t = blockIdx.x;
    const int tid = threadIdx.x;
    const int c0 = tid * 8;
    const float* zrow = P + (size_t)t * NPROJ_PAD + COL_Z + c0;
    const float4 z0 = *(const float4*)zrow;
    const float4 z1 = *(const float4*)(zrow + 4);
    const float zz[8] = { z0.x, z0.y, z0.z, z0.w, z1.x, z1.y, z1.z, z1.w };
    const float* xrow = xconv + (size_t)t * D_INNER + c0;
    const float4 x0 = *(const float4*)xrow;
    const float4 x1 = *(const float4*)(xrow + 4);
    const float xx[8] = { x0.x, x0.y, x0.z, x0.w, x1.x, x1.y, x1.z, x1.w };
    const float4 d0 = *(const float4*)&Dp[c0];
    const float4 d1 = *(const float4*)&Dp[c0 + 4];
    const float dd[8] = { d0.x, d0.y, d0.z, d0.w, d1.x, d1.y, d1.z, d1.w };
    const float* yrow = ygt + (size_t)t * D_INNER + c0;
    const float4 y0 = *(const float4*)yrow;
    const float4 y1 = *(const float4*)(yrow + 4);
    const float yy[8] = { y0.x, y0.y, y0.z, y0.w, y1.x, y1.y, y1.z, y1.w };
    float v[8];
    float ss = 0.f;
    #pragma unroll
    for (int j = 0; j < 8; ++j) {
        const float yv = yy[j] + dd[j] * xx[j];
        const float z = zz[j];
        const float gated = yv * (z / (1.f + __expf(-z)));
        v[j] = gated;
        ss += gated * gated;
    }
    #pragma unroll
    for (int off = 32; off > 0; off >>= 1) ss += __shfl_xor(ss, off);
    const int wave = tid >> 6;
    if ((tid & 63) == 0) red[wave] = ss;
    __syncthreads();
    const float total = red[0] + red[1] + red[2] + red[3];
    const float scale = rsqrtf(total * (1.f / D_INNER) + 1e-6f);
    u16 o[8];
    #pragma unroll
    for (int j = 0; j < 8; ++j)
        o[j] = f2bf(v[j] * scale * nw[c0 + j]);
    *(uint4*)&Yb[(size_t)t * D_INNER + c0] = *(uint4*)o;
}

// ---------- launcher ----------
extern "C" void kernel_launch(void* const* d_in, const int* in_sizes, int n_in,
                              void* d_out, int out_size, void* d_ws, size_t ws_size,
                              hipStream_t stream)
{
    const float* x      = (const float*)d_in[0];
    const float* W_in   = (const float*)d_in[1];
    const float* W_conv = (const float*)d_in[2];
    const float* b_conv = (const float*)d_in[3];
    const float* A_log  = (const float*)d_in[4];
    const float* Dp     = (const float*)d_in[5];
    const float* dt_bias= (const float*)d_in[6];
    const float* norm_w = (const float*)d_in[7];
    const float* W_out  = (const float*)d_in[8];
    float* out = (float*)d_out;

    // Workspace layout (MiB). Cex consumed by conv_dt (dead before scan).
    char* w = (char*)d_ws;
    u16*   xb_hi  = (u16*)(w);                         //  0-2   (dead after GEMM1)
    u16*   xb_lo  = (u16*)(w + (2u  << 20));           //  2-4   (dead after GEMM1)
    u16*   Winb   = (u16*)(w + (4u  << 20));           //  4-12.5(dead after GEMM1)
    u16*   Winb_lo= (u16*)(w + (12u << 20) + (512u << 10)); // 12.5-13 (dead after GEMM1)
    float* Cex    = (float*)(w + (13u << 20));         // 13-15  (dead after conv_dt)
    u16*   Yb     = (u16*)(w);                         //  0-4   (after GEMM1 inputs dead)
    u16*   S      = (u16*)(w + (8u  << 20));           //  8-16  bf16 [hd][32][64]
    u16*   Woutb  = (u16*)(w + (16u << 20));           // 16-20
    float* P      = (float*)(w + (20u << 20));         // 20-37  (1024x4352)
    float* xconv  = (float*)(w + (37u << 20));         // 37-45
    float* gT     = (float*)(w + (45u << 20));         // 45-45.125 [h][t]
    float* dtsT   = (float*)(w + (45u << 20) + (128u << 10)); // 45.125-45.25 [h][t]
    float2* BCp2  = (float2*)(w + (45u << 20) + (512u << 10)); // 45.5-46 [t][64]
    float* ygt    = (float*)(w + (46u << 20));         // 46-54  [t][hd]
    float* xT     = (float*)(w + (54u << 20));         // 54-62  [hd][t]

    const u16* Winb_lo_virt = Winb_lo - (size_t)4096 * DIM;

    // 1. input casts (x, W_in); W_out cast deferred into conv_dt
    cast_all_kernel<<<dim3(5632), 256, 0, stream>>>(
        x, W_in, xb_hi, xb_lo, Winb, Winb_lo);

    // 2. in-projection GEMM, load-balanced: 1024 normal + 192 precise-slice blocks
    gemm_bt64<<<dim3(1024 + 192), 256, 0, stream>>>(
        xb_hi, xb_lo, Winb, Winb_lo_virt, P, Cex, DIM, NPROJ_PAD, 64, 16);

    // 3. fused conv+SiLU+xT | dtscan + BC pack | W_out cast
    conv_dt_kernel<<<dim3(256 + 128 + 2048), 256, 0, stream>>>(
        P, Cex, W_conv, b_conv, dt_bias, W_out, xconv, xT, BCp2, gT, dtsT, Woutb);

    // 4. chunked selective scan (16 d x 1 chunk per wave, inline decay)
    scan_local_kernel<<<dim3(D_INNER / 16, 16), 128, 0, stream>>>(
        BCp2, dtsT, A_log, xT, ygt, S);
    chunk_combine_kernel<<<dim3(D_INNER * 64 / 256), 256, 0, stream>>>(A_log, gT, S);
    scan_cross_mfma<<<dim3(N_HEADS * NCHUNK / 4), 256, 0, stream>>>(BCp2, gT, A_log, S, ygt);

    // 5. skip + gate + RMSNorm + bf16 cast
    rmsnorm_kernel<<<dim3(L_SEQ), 256, 0, stream>>>(ygt, P, xconv, Dp, norm_w, Yb);

    // 6. out-projection GEMM: out = Y @ W_out^T (256 uniform blocks)
    gemm_bt64<<<dim3(256), 256, 0, stream>>>(
        Yb, (const u16*)nullptr, Woutb, (const u16*)nullptr, out, (float*)nullptr,
        D_INNER, DIM, 16, 16);
}